// Round 8
// baseline (326.544 us; speedup 1.0000x reference)
//
#include <hip/hip_runtime.h>
#include <hip/hip_bf16.h>

#define B_  2
#define L_  2048
#define HS_ 2048
#define NH_ 16
#define NKV_ 4
#define HD_ 128
#define EPS_ 1e-6f
#define SCALE_ 0.08838834764831843f
#define LOG2E_ 1.4426950408889634f

typedef __attribute__((ext_vector_type(8))) short bf16x8;
typedef __attribute__((ext_vector_type(4))) float f32x4;

__device__ __forceinline__ f32x4 mfma16(bf16x8 a, bf16x8 b, f32x4 c) {
    return __builtin_amdgcn_mfma_f32_16x16x32_bf16(a, b, c, 0, 0, 0);
}

__device__ __forceinline__ void async_copy16(void* lds, const void* g) {
    __builtin_amdgcn_global_load_lds(
        (const __attribute__((address_space(1))) unsigned int*)g,
        (__attribute__((address_space(3))) unsigned int*)lds,
        16, 0, 0);
}

// Single-instruction RNE f32 pair -> packed bf16.
__device__ __forceinline__ unsigned cvtpk(float lo, float hi) {
    unsigned r;
    asm("v_cvt_pk_bf16_f32 %0, %1, %2" : "=v"(r) : "v"(lo), "v"(hi));
    return r;
}

// ---------------------------------------------------------------------------
// fused_prep: one launch covering hidden cvt + 4 weight transposes.
__global__ __launch_bounds__(256) void fused_prep(
    const float* __restrict__ hidden, __hip_bfloat16* __restrict__ A_h,
    const float* __restrict__ Wq, __hip_bfloat16* __restrict__ Wq_t,
    const float* __restrict__ Wk, __hip_bfloat16* __restrict__ Wk_t,
    const float* __restrict__ Wv, __hip_bfloat16* __restrict__ Wv_t,
    const float* __restrict__ Wo, __hip_bfloat16* __restrict__ Wo_t) {
    __shared__ float tile[32][33];
    int bid = blockIdx.x;
    if (bid < 8192) {
        int i = bid * 256 + threadIdx.x;
        float4 v = ((const float4*)hidden)[i];
        union { __hip_bfloat16 h[4]; short4 s; } u;
        u.h[0] = __float2bfloat16(v.x);
        u.h[1] = __float2bfloat16(v.y);
        u.h[2] = __float2bfloat16(v.z);
        u.h[3] = __float2bfloat16(v.w);
        ((short4*)A_h)[i] = u.s;
        return;
    }
    const float* src; __hip_bfloat16* dst; int N, tb;
    if (bid < 12288)      { tb = bid - 8192;  src = Wq; dst = Wq_t; N = 2048; }
    else if (bid < 13312) { tb = bid - 12288; src = Wk; dst = Wk_t; N = 512;  }
    else if (bid < 14336) { tb = bid - 13312; src = Wv; dst = Wv_t; N = 512;  }
    else                  { tb = bid - 14336; src = Wo; dst = Wo_t; N = 2048; }
    int nt = N >> 5;
    int n0 = (tb % nt) * 32, k0 = (tb / nt) * 32;
    int tx = threadIdx.x & 31, ty = threadIdx.x >> 5;
#pragma unroll
    for (int i = 0; i < 32; i += 8)
        tile[ty + i][tx] = src[(size_t)(k0 + ty + i) * N + n0 + tx];
    __syncthreads();
#pragma unroll
    for (int i = 0; i < 32; i += 8)
        dst[(size_t)(n0 + ty + i) * HS_ + k0 + tx] = __float2bfloat16(tile[tx][ty + i]);
}

// ---------------------------------------------------------------------------
// fused_norm_v: Q norm_rope + K norm_rope + V transpose in one launch.
__device__ __forceinline__ void norm_rope_row(const float* __restrict__ X,
                                              __hip_bfloat16* __restrict__ Y,
                                              const float* __restrict__ w,
                                              int row, int lane,
                                              int log2nh, int in_stride, float oscale) {
    int m = row >> log2nh;
    int head = row & ((1 << log2nh) - 1);
    int pos = m & (L_ - 1);
    const float* x = X + (size_t)m * in_stride + head * HD_;
    float x1 = x[lane], x2 = x[lane + 64];
    float ss = x1 * x1 + x2 * x2;
#pragma unroll
    for (int mm = 1; mm < 64; mm <<= 1) ss += __shfl_xor(ss, mm);
    float rms = rsqrtf(ss * (1.0f / 128.0f) + EPS_);
    float xn1 = x1 * rms * w[lane];
    float xn2 = x2 * rms * w[lane + 64];
    float inv_freq = __builtin_exp2f(-(float)lane * 0.20762050593046014f);
    float ang = (float)pos * inv_freq;
    float c = cosf(ang), s = sinf(ang);
    __hip_bfloat16* y = Y + (size_t)row * HD_;
    y[lane]      = __float2bfloat16((xn1 * c - xn2 * s) * oscale);
    y[lane + 64] = __float2bfloat16((xn2 * c + xn1 * s) * oscale);
}

__global__ __launch_bounds__(256) void fused_norm_v(
    const float* __restrict__ q_f32, __hip_bfloat16* __restrict__ q_bf,
    const float* __restrict__ kv_f32, __hip_bfloat16* __restrict__ k_bf,
    __hip_bfloat16* __restrict__ vt_bf,
    const float* __restrict__ qw, const float* __restrict__ kw) {
    __shared__ float tile[32][33];
    int bid = blockIdx.x;
    int lane = threadIdx.x & 63;
    if (bid < 16384) {
        int row = bid * 4 + (threadIdx.x >> 6);
        norm_rope_row(q_f32, q_bf, qw, row, lane, 4, 2048, SCALE_ * LOG2E_);
        return;
    }
    if (bid < 20480) {
        int row = (bid - 16384) * 4 + (threadIdx.x >> 6);
        norm_rope_row(kv_f32, k_bf, kw, row, lane, 2, 1024, 1.0f);
        return;
    }
    int vbid = bid - 20480;
    int xb = vbid & 63, yb = (vbid >> 6) & 3, zb = vbid >> 8;
    int b = zb >> 2, kv = zb & 3;
    int l0 = xb * 32, d0 = yb * 32;
    int tx = threadIdx.x & 31, ty = threadIdx.x >> 5;
#pragma unroll
    for (int i = 0; i < 32; i += 8)
        tile[ty + i][tx] = kv_f32[(size_t)(b * L_ + l0 + ty + i) * 1024 + 512 + kv * HD_ + d0 + tx];
    __syncthreads();
#pragma unroll
    for (int i = 0; i < 32; i += 8)
        vt_bf[((size_t)(b * NKV_ + kv) * HD_ + d0 + ty + i) * L_ + l0 + tx] =
            __float2bfloat16(tile[tx][ty + i]);
}

// ---------------------------------------------------------------------------
// 256x256 8-phase GEMM (unchanged, verified). K=2048.
#define GNT 32
#define GKB 4096   // K=2048 * 2B row stride
__global__ __launch_bounds__(512, 2) void gemm8_bf16(const __hip_bfloat16* __restrict__ A,
                                                     const __hip_bfloat16* __restrict__ Bt,
                                                     float* __restrict__ C1,
                                                     float* __restrict__ C2,
                                                     int Ntot, int splitN) {
    __shared__ __align__(16) char lds[131072];
    int t = threadIdx.x;
    int w = t >> 6, lane = t & 63;
    int row16 = lane & 15, quad = lane >> 4, e7 = row16 & 7;
    int wr = w >> 2, wc = w & 3;

    int gx = gridDim.x;
    int nwg = gx * gridDim.y;
    int bid = blockIdx.y * gx + blockIdx.x;
    int cpx = nwg >> 3;
    int swz = (bid & 7) * cpx + (bid >> 3);
    int bx = swz % gx, by = swz / gx;
    int m0 = bx * 256, n0 = by * 256;

    const char* baseA[2];
    const char* baseB[2];
#pragma unroll
    for (int kc = 0; kc < 2; ++kc) {
        int so = ((kc * 4 + quad) ^ e7) << 4;
        baseA[kc] = lds + wr * 16384 + row16 * 128 + so;
        baseB[kc] = lds + 65536 + wc * 8192 + row16 * 128 + so;
    }

    int r8 = lane >> 3;
    int sl = (lane & 7) ^ r8;
    char* dstA = lds + wr * 16384 + (w & 3) * 2048 + lane * 16;
    char* dstB = lds + 65536 + (w >> 1) * 8192 + (w & 1) * 2048 + lane * 16;
    const char* gA = (const char*)A +
        (size_t)(m0 + wr * 128 + (w & 3) * 16 + r8) * GKB + sl * 16;
    const char* gB = (const char*)Bt +
        (size_t)(n0 + (w >> 1) * 64 + (w & 1) * 16 + r8) * GKB + sl * 16;

    f32x4 acc[8][4] = {};
    bf16x8 a[4][2], b[2][2];

#pragma unroll
    for (int i = 0; i < 2; ++i) async_copy16(dstA + i * 1024, gA + i * 32768);
#pragma unroll
    for (int i = 0; i < 2; ++i) async_copy16(dstB + i * 1024, gB + i * 32768);
#pragma unroll
    for (int i = 0; i < 2; ++i) async_copy16(dstB + 4096 + i * 1024, gB + 131072 + i * 32768);
#pragma unroll
    for (int i = 0; i < 2; ++i) async_copy16(dstA + 8192 + i * 1024, gA + 262144 + i * 32768);

    for (int Tb = 0; Tb < GNT; Tb += 2) {
#pragma unroll
        for (int u = 0; u < 2; ++u) {
            const int T = Tb + u;
            const int cu = u * 32768, du = (u ^ 1) * 32768;
            const int tn = (T + 1 < GNT ? T + 1 : T) * 128;

            asm volatile("s_waitcnt vmcnt(4)" ::: "memory");
            __builtin_amdgcn_s_barrier();
            __builtin_amdgcn_sched_barrier(0);
#pragma unroll
            for (int mi = 0; mi < 4; ++mi)
#pragma unroll
                for (int kc = 0; kc < 2; ++kc)
                    a[mi][kc] = *(const bf16x8*)(baseA[kc] + cu + mi * 2048);
#pragma unroll
            for (int ni = 0; ni < 2; ++ni)
#pragma unroll
                for (int kc = 0; kc < 2; ++kc)
                    b[ni][kc] = *(const bf16x8*)(baseB[kc] + cu + ni * 2048);
#pragma unroll
            for (int i = 0; i < 2; ++i)
                async_copy16(dstA + du + i * 1024, gA + tn + i * 32768);
            asm volatile("s_waitcnt lgkmcnt(0)" ::: "memory");
            __builtin_amdgcn_sched_barrier(0);
            __builtin_amdgcn_s_setprio(1);
#pragma unroll
            for (int mi = 0; mi < 4; ++mi)
#pragma unroll
                for (int ni = 0; ni < 2; ++ni)
#pragma unroll
                    for (int kc = 0; kc < 2; ++kc)
                        acc[mi][ni] = mfma16(a[mi][kc], b[ni][kc], acc[mi][ni]);
            __builtin_amdgcn_s_setprio(0);

            asm volatile("s_waitcnt vmcnt(4)" ::: "memory");
            __builtin_amdgcn_s_barrier();
            __builtin_amdgcn_sched_barrier(0);
#pragma unroll
            for (int ni = 0; ni < 2; ++ni)
#pragma unroll
                for (int kc = 0; kc < 2; ++kc)
                    b[ni][kc] = *(const bf16x8*)(baseB[kc] + cu + 4096 + ni * 2048);
#pragma unroll
            for (int i = 0; i < 2; ++i)
                async_copy16(dstB + du + i * 1024, gB + tn + i * 32768);
            asm volatile("s_waitcnt lgkmcnt(0)" ::: "memory");
            __builtin_amdgcn_sched_barrier(0);
            __builtin_amdgcn_s_setprio(1);
#pragma unroll
            for (int mi = 0; mi < 4; ++mi)
#pragma unroll
                for (int ni = 0; ni < 2; ++ni)
#pragma unroll
                    for (int kc = 0; kc < 2; ++kc)
                        acc[mi][2 + ni] = mfma16(a[mi][kc], b[ni][kc], acc[mi][2 + ni]);
            __builtin_amdgcn_s_setprio(0);

            asm volatile("s_waitcnt vmcnt(4)" ::: "memory");
            __builtin_amdgcn_s_barrier();
            __builtin_amdgcn_sched_barrier(0);
#pragma unroll
            for (int mi = 0; mi < 4; ++mi)
#pragma unroll
                for (int kc = 0; kc < 2; ++kc)
                    a[mi][kc] = *(const bf16x8*)(baseA[kc] + cu + 8192 + mi * 2048);
#pragma unroll
            for (int i = 0; i < 2; ++i)
                async_copy16(dstB + du + 4096 + i * 1024, gB + 131072 + tn + i * 32768);
            asm volatile("s_waitcnt lgkmcnt(0)" ::: "memory");
            __builtin_amdgcn_sched_barrier(0);
            __builtin_amdgcn_s_setprio(1);
#pragma unroll
            for (int mi = 0; mi < 4; ++mi)
#pragma unroll
                for (int ni = 0; ni < 2; ++ni)
#pragma unroll
                    for (int kc = 0; kc < 2; ++kc)
                        acc[4 + mi][2 + ni] = mfma16(a[mi][kc], b[ni][kc], acc[4 + mi][2 + ni]);
            __builtin_amdgcn_s_setprio(0);

            __builtin_amdgcn_s_barrier();
            __builtin_amdgcn_sched_barrier(0);
#pragma unroll
            for (int ni = 0; ni < 2; ++ni)
#pragma unroll
                for (int kc = 0; kc < 2; ++kc)
                    b[ni][kc] = *(const bf16x8*)(baseB[kc] + cu + ni * 2048);
#pragma unroll
            for (int i = 0; i < 2; ++i)
                async_copy16(dstA + du + 8192 + i * 1024, gA + 262144 + tn + i * 32768);
            asm volatile("s_waitcnt lgkmcnt(0)" ::: "memory");
            __builtin_amdgcn_sched_barrier(0);
            __builtin_amdgcn_s_setprio(1);
#pragma unroll
            for (int mi = 0; mi < 4; ++mi)
#pragma unroll
                for (int ni = 0; ni < 2; ++ni)
#pragma unroll
                    for (int kc = 0; kc < 2; ++kc)
                        acc[4 + mi][ni] = mfma16(a[mi][kc], b[ni][kc], acc[4 + mi][ni]);
            __builtin_amdgcn_s_setprio(0);
        }
    }

    float* Cb; int cs, ccol0;
    if (n0 < splitN) { Cb = C1; cs = splitN; ccol0 = n0; }
    else             { Cb = C2; cs = Ntot - splitN; ccol0 = n0 - splitN; }
#pragma unroll
    for (int mi = 0; mi < 8; ++mi)
#pragma unroll
        for (int ni = 0; ni < 4; ++ni) {
            int rbase = m0 + wr * 128 + mi * 16 + quad * 4;
            int col = ccol0 + wc * 64 + ni * 16 + row16;
#pragma unroll
            for (int r = 0; r < 4; ++r)
                Cb[(size_t)(rbase + r) * cs + col] = acc[mi][ni][r];
        }
}

// ---------------------------------------------------------------------------
// 128x256-tile pipelined GEMM for the O-projection (unchanged, verified).
__global__ __launch_bounds__(512, 2) void gemm_o(const __hip_bfloat16* __restrict__ A,
                                                 const __hip_bfloat16* __restrict__ Bt,
                                                 float* __restrict__ C) {
    __shared__ __align__(16) char lds[98304];
    int t = threadIdx.x;
    int w = t >> 6, lane = t & 63;
    int row16 = lane & 15, quad = lane >> 4, e7 = row16 & 15 & 7;
    int wr = w >> 2, wc = w & 3;

    int gx = gridDim.x;
    int nwg = gx * gridDim.y;
    int bid = blockIdx.y * gx + blockIdx.x;
    int cpx = nwg >> 3;
    int swz = (bid & 7) * cpx + (bid >> 3);
    int bx = swz % gx, by = swz / gx;
    int m0 = bx * 128, n0 = by * 256;

    const char* baseA[2];
    const char* baseB[2];
#pragma unroll
    for (int kc = 0; kc < 2; ++kc) {
        int so = ((kc * 4 + quad) ^ e7) << 4;
        baseA[kc] = lds + wr * 8192 + row16 * 128 + so;
        baseB[kc] = lds + 32768 + wc * 8192 + row16 * 128 + so;
    }

    int r8 = lane >> 3;
    int sl = (lane & 7) ^ r8;
    int arow_lo = ((w & 4) << 4) + (w & 3) * 8;
    int li0 = w * 2;
    int brow_lo0 = ((li0) >> 2) * 64 + ((li0) & 3) * 8;
    int brow_lo1 = ((li0 + 1) >> 2) * 64 + ((li0 + 1) & 3) * 8;

    char* dAlo = lds + arow_lo * 128 + lane * 16;
    char* dBlo0 = lds + 32768 + brow_lo0 * 128 + lane * 16;
    char* dBlo1 = lds + 32768 + brow_lo1 * 128 + lane * 16;
    const char* gAlo = (const char*)A + (size_t)(m0 + arow_lo + r8) * GKB + sl * 16;
    const char* gBlo0 = (const char*)Bt + (size_t)(n0 + brow_lo0 + r8) * GKB + sl * 16;
    const char* gBlo1 = (const char*)Bt + (size_t)(n0 + brow_lo1 + r8) * GKB + sl * 16;
    const int HI_L = 32 * 128;
    const size_t HI_G = (size_t)32 * GKB;

    f32x4 acc[4][4] = {};
    bf16x8 a[2][2], b[2][2];

    async_copy16(dAlo, gAlo);
    async_copy16(dBlo0, gBlo0);
    async_copy16(dBlo1, gBlo1);
    async_copy16(dBlo0 + HI_L, gBlo0 + HI_G);
    async_copy16(dBlo1 + HI_L, gBlo1 + HI_G);
    async_copy16(dAlo + HI_L, gAlo + HI_G);

    for (int Tb = 0; Tb < GNT; Tb += 2) {
#pragma unroll
        for (int u = 0; u < 2; ++u) {
            const int T = Tb + u;
            const int cuA = u * 16384, duA = (u ^ 1) * 16384;
            const int cuB = u * 32768, duB = (u ^ 1) * 32768;
            const int tn = (T + 1 < GNT ? T + 1 : T) * 128;

            asm volatile("s_waitcnt vmcnt(3)" ::: "memory");
            __builtin_amdgcn_s_barrier();
            __builtin_amdgcn_sched_barrier(0);
#pragma unroll
            for (int mi = 0; mi < 2; ++mi)
#pragma unroll
                for (int kc = 0; kc < 2; ++kc)
                    a[mi][kc] = *(const bf16x8*)(baseA[kc] + cuA + mi * 2048);
#pragma unroll
            for (int ni = 0; ni < 2; ++ni)
#pragma unroll
                for (int kc = 0; kc < 2; ++kc)
                    b[ni][kc] = *(const bf16x8*)(baseB[kc] + cuB + ni * 2048);
            async_copy16(dAlo + duA, gAlo + tn);
            asm volatile("s_waitcnt lgkmcnt(0)" ::: "memory");
            __builtin_amdgcn_sched_barrier(0);
            __builtin_amdgcn_s_setprio(1);
#pragma unroll
            for (int mi = 0; mi < 2; ++mi)
#pragma unroll
                for (int ni = 0; ni < 2; ++ni)
#pragma unroll
                    for (int kc = 0; kc < 2; ++kc)
                        acc[mi][ni] = mfma16(a[mi][kc], b[ni][kc], acc[mi][ni]);
            __builtin_amdgcn_s_setprio(0);

            asm volatile("s_waitcnt vmcnt(2)" ::: "memory");
            __builtin_amdgcn_s_barrier();
            __builtin_amdgcn_sched_barrier(0);
#pragma unroll
            for (int ni = 0; ni < 2; ++ni)
#pragma unroll
                for (int kc = 0; kc < 2; ++kc)
                    b[ni][kc] = *(const bf16x8*)(baseB[kc] + cuB + 4096 + ni * 2048);
            async_copy16(dBlo0 + duB, gBlo0 + tn);
            async_copy16(dBlo1 + duB, gBlo1 + tn);
            asm volatile("s_waitcnt lgkmcnt(0)" ::: "memory");
            __builtin_amdgcn_sched_barrier(0);
            __builtin_amdgcn_s_setprio(1);
#pragma unroll
            for (int mi = 0; mi < 2; ++mi)
#pragma unroll
                for (int ni = 0; ni < 2; ++ni)
#pragma unroll
                    for (int kc = 0; kc < 2; ++kc)
                        acc[mi][2 + ni] = mfma16(a[mi][kc], b[ni][kc], acc[mi][2 + ni]);
            __builtin_amdgcn_s_setprio(0);

            asm volatile("s_waitcnt vmcnt(3)" ::: "memory");
            __builtin_amdgcn_s_barrier();
            __builtin_amdgcn_sched_barrier(0);
#pragma unroll
            for (int mi = 0; mi < 2; ++mi)
#pragma unroll
                for (int kc = 0; kc < 2; ++kc)
                    a[mi][kc] = *(const bf16x8*)(baseA[kc] + cuA + 4096 + mi * 2048);
            async_copy16(dBlo0 + HI_L + duB, gBlo0 + HI_G + tn);
            async_copy16(dBlo1 + HI_L + duB, gBlo1 + HI_G + tn);
            asm volatile("s_waitcnt lgkmcnt(0)" ::: "memory");
            __builtin_amdgcn_sched_barrier(0);
            __builtin_amdgcn_s_setprio(1);
#pragma unroll
            for (int mi = 0; mi < 2; ++mi)
#pragma unroll
                for (int ni = 0; ni < 2; ++ni)
#pragma unroll
                    for (int kc = 0; kc < 2; ++kc)
                        acc[2 + mi][2 + ni] = mfma16(a[mi][kc], b[ni][kc], acc[2 + mi][2 + ni]);
            __builtin_amdgcn_s_setprio(0);

            __builtin_amdgcn_s_barrier();
            __builtin_amdgcn_sched_barrier(0);
#pragma unroll
            for (int ni = 0; ni < 2; ++ni)
#pragma unroll
                for (int kc = 0; kc < 2; ++kc)
                    b[ni][kc] = *(const bf16x8*)(baseB[kc] + cuB + ni * 2048);
            async_copy16(dAlo + HI_L + duA, gAlo + HI_G + tn);
            asm volatile("s_waitcnt lgkmcnt(0)" ::: "memory");
            __builtin_amdgcn_sched_barrier(0);
            __builtin_amdgcn_s_setprio(1);
#pragma unroll
            for (int mi = 0; mi < 2; ++mi)
#pragma unroll
                for (int ni = 0; ni < 2; ++ni)
#pragma unroll
                    for (int kc = 0; kc < 2; ++kc)
                        acc[2 + mi][ni] = mfma16(a[mi][kc], b[ni][kc], acc[2 + mi][ni]);
            __builtin_amdgcn_s_setprio(0);
        }
    }
    asm volatile("s_waitcnt vmcnt(0)" ::: "memory");

#pragma unroll
    for (int mi = 0; mi < 4; ++mi)
#pragma unroll
        for (int ni = 0; ni < 4; ++ni) {
            int rbase = m0 + wr * 64 + mi * 16 + quad * 4;
            int col = n0 + wc * 64 + ni * 16 + row16;
#pragma unroll
            for (int r = 0; r < 4; ++r)
                C[(size_t)(rbase + r) * 2048 + col] = acc[mi][ni][r];
        }
}

// ---------------------------------------------------------------------------
// Flash attention v8 (verified 4-wave x 16-row structure), split by batch:
// b comes from the bb argument so each dispatch is ~37 us and the projection
// GEMMs become visible in the rocprof top-5 table.
__global__ __launch_bounds__(256, 2) void flash_attn(const __hip_bfloat16* __restrict__ Q,
                                                     const __hip_bfloat16* __restrict__ Kb,
                                                     const __hip_bfloat16* __restrict__ Vt,
                                                     __hip_bfloat16* __restrict__ O,
                                                     int bb) {
    __shared__ __align__(16) __hip_bfloat16 sK[2][64 * 128];
    __shared__ __align__(16) __hip_bfloat16 sV[2][128 * 64];
    __shared__ __align__(16) __hip_bfloat16 sP[4][16 * 72];

    int t = threadIdx.x, wave = t >> 6, lane = t & 63;
    int row16 = lane & 15, quad = lane >> 4;
    int h = blockIdx.y, b = bb;
    int kv = h & (NKV_ - 1);
    int x = blockIdx.x;
    int qtA = x, qtB = 31 - x;
    int nA = qtA + 1;
    const int nTot = 33;

    int e7 = row16 & 7;
    int kOff[4], vOff[2];
#pragma unroll
    for (int kc = 0; kc < 4; ++kc)
        kOff[kc] = row16 * 256 + (((kc * 4 + quad) ^ e7) * 16);
#pragma unroll
    for (int kc2 = 0; kc2 < 2; ++kc2)
        vOff[kc2] = row16 * 128 + (((kc2 * 4 + quad) ^ e7) * 16);

    const char* sKb = (const char*)&sK[0][0];
    const char* sVb = (const char*)&sV[0][0];
    char* myP = (char*)&sP[wave][0];
    int pW = row16 * 144 + quad * 8;
    int pR = row16 * 144 + quad * 16;

    const char* gK[4];
    const char* gV[4];
#pragma unroll
    for (int i = 0; i < 4; ++i) {
        int rk = wave * 16 + i * 4 + quad;
        int ck = row16 ^ (rk & 7);
        gK[i] = (const char*)(Kb + ((size_t)(b * L_ + rk) * NKV_ + kv) * HD_ + ck * 8);
        int rv = wave * 32 + i * 8 + (lane >> 3);
        int cv = (lane & 7) ^ (rv & 7);
        gV[i] = (const char*)(Vt + ((size_t)(b * NKV_ + kv) * HD_ + rv) * L_ + cv * 8);
    }
    char* dK = (char*)&sK[0][0] + wave * 4096 + lane * 16;
    char* dV = (char*)&sV[0][0] + wave * 4096 + lane * 16;

    bf16x8 qf[4];
    f32x4 accO[8];
    float lrow;
    int q0w = 0;

    auto loadQ = [&](int qt) {
        q0w = qt * 64 + wave * 16;
        const __hip_bfloat16* qbase =
            Q + ((size_t)(b * L_ + q0w + row16) * NH_ + h) * HD_ + quad * 8;
#pragma unroll
        for (int kc = 0; kc < 4; ++kc) qf[kc] = *(const bf16x8*)(qbase + kc * 32);
#pragma unroll
        for (int db = 0; db < 8; ++db) accO[db] = f32x4{0.f, 0.f, 0.f, 0.f};
        lrow = 0.f;
    };

    auto epilogue = [&]() {
        float l = lrow;
        l += __shfl_xor(l, 16);
        l += __shfl_xor(l, 32);
        float linv = 1.0f / l;
        __hip_bfloat16* obase = O + ((size_t)(b * L_ + q0w + row16) * NH_ + h) * HD_;
#pragma unroll
        for (int db = 0; db < 8; ++db) {
            union { __hip_bfloat16 h4[4]; short4 s4; } u;
#pragma unroll
            for (int r = 0; r < 4; ++r) u.h4[r] = __float2bfloat16(accO[db][r] * linv);
            *(short4*)(obase + db * 16 + quad * 4) = u.s4;
        }
    };

    auto stage = [&](int s1) {
        int kb64 = (s1 < nA ? s1 : s1 - nA) * 64;
        int buf = (s1 & 1) * 16384;
        int ko = kb64 * 1024;
        int vo = kb64 * 2;
#pragma unroll
        for (int i = 0; i < 4; ++i) {
            async_copy16(dK + buf + i * 1024, gK[i] + ko);
            async_copy16(dV + buf + i * 1024, gV[i] + vo);
        }
    };

    loadQ(qtA);
    stage(0);
    for (int s = 0; s < nTot; ++s) {
        __syncthreads();
        if (s + 1 < nTot) stage(s + 1);
        if (s == nA) { epilogue(); loadQ(qtB); }
        int kcur = (s < nA ? s : s - nA) * 64;
        const char* cK = sKb + (s & 1) * 16384;
        const char* cV = sVb + (s & 1) * 16384;

        f32x4 st[4];
        __builtin_amdgcn_s_setprio(1);
#pragma unroll
        for (int kb = 0; kb < 4; ++kb) {
            f32x4 acc = {};
#pragma unroll
            for (int kc = 0; kc < 4; ++kc) {
                bf16x8 kf = *(const bf16x8*)(cK + kb * 4096 + kOff[kc]);
                acc = mfma16(kf, qf[kc], acc);
            }
            st[kb] = acc;
        }
        __builtin_amdgcn_s_setprio(0);

        float p[4][4];
        if (kcur + 63 > q0w) {
            int qgRel = q0w + row16 - kcur - quad * 4;
#pragma unroll
            for (int kb = 0; kb < 4; ++kb)
#pragma unroll
                for (int r = 0; r < 4; ++r) {
                    float e = __builtin_exp2f(st[kb][r]);
                    p[kb][r] = (kb * 16 + r <= qgRel) ? e : 0.f;
                }
        } else {
#pragma unroll
            for (int kb = 0; kb < 4; ++kb)
#pragma unroll
                for (int r = 0; r < 4; ++r)
                    p[kb][r] = __builtin_exp2f(st[kb][r]);
        }
#pragma unroll
        for (int kb = 0; kb < 4; ++kb)
#pragma unroll
            for (int r = 0; r < 4; ++r) lrow += p[kb][r];

#pragma unroll
        for (int kb = 0; kb < 4; ++kb) {
            uint2 u;
            u.x = cvtpk(p[kb][0], p[kb][1]);
            u.y = cvtpk(p[kb][2], p[kb][3]);
            *(uint2*)(myP + pW + kb * 32) = u;
        }
        asm volatile("s_waitcnt lgkmcnt(0)" ::: "memory");
        bf16x8 pf[2];
        pf[0] = *(const bf16x8*)(myP + pR);
        pf[1] = *(const bf16x8*)(myP + pR + 64);

        __builtin_amdgcn_s_setprio(1);
#pragma unroll
        for (int db = 0; db < 8; ++db) {
#pragma unroll
            for (int kc2 = 0; kc2 < 2; ++kc2) {
                bf16x8 vf = *(const bf16x8*)(cV + db * 2048 + vOff[kc2]);
                accO[db] = mfma16(vf, pf[kc2], accO[db]);
            }
        }
        __builtin_amdgcn_s_setprio(0);
    }
    epilogue();
}

// ---------------------------------------------------------------------------
extern "C" void kernel_launch(void* const* d_in, const int* in_sizes, int n_in,
                              void* d_out, int out_size, void* d_ws, size_t ws_size,
                              hipStream_t stream) {
    const float* hidden = (const float*)d_in[0];
    const float* Wq = (const float*)d_in[1];
    const float* Wk = (const float*)d_in[2];
    const float* Wv = (const float*)d_in[3];
    const float* Wo = (const float*)d_in[4];
    const float* qw = (const float*)d_in[5];
    const float* kw = (const float*)d_in[6];
    float* out = (float*)d_out;

    char* ws = (char*)d_ws;
    size_t off = 0;
    auto alloc = [&](size_t bytes) { char* p = ws + off; off += (bytes + 255) & ~255ull; return p; };
    __hip_bfloat16* Wq_t = (__hip_bfloat16*)alloc((size_t)HS_ * NH_ * HD_ * 2);   // 8 MB
    __hip_bfloat16* Wk_t = (__hip_bfloat16*)alloc((size_t)HS_ * NKV_ * HD_ * 2);  // 2 MB (contiguous after Wq_t)
    __hip_bfloat16* Wv_t = (__hip_bfloat16*)alloc((size_t)HS_ * NKV_ * HD_ * 2);  // 2 MB (contiguous after Wk_t)
    __hip_bfloat16* Wo_t = (__hip_bfloat16*)alloc((size_t)HS_ * NH_ * HD_ * 2);   // 8 MB
    __hip_bfloat16* A_h  = (__hip_bfloat16*)alloc((size_t)B_ * L_ * HS_ * 2);     // 16 MB; reused as attn_bf
    float* kv_f32 = (float*)alloc((size_t)B_ * L_ * 1024 * 4);                    // 16 MB [M,1024] = K|V
    __hip_bfloat16* q_bf  = (__hip_bfloat16*)alloc((size_t)B_ * L_ * NH_ * HD_ * 2);
    __hip_bfloat16* k_bf  = (__hip_bfloat16*)alloc((size_t)B_ * L_ * NKV_ * HD_ * 2);
    __hip_bfloat16* vt_bf = (__hip_bfloat16*)alloc((size_t)B_ * NKV_ * HD_ * L_ * 2);
    float* q_f32 = out;                     // reuse d_out as pre-norm Q scratch
    __hip_bfloat16* attn_bf = A_h;

    const int M = B_ * L_;

    // 1) hidden cvt + all 4 weight transposes in one launch
    fused_prep<<<18432, 256, 0, stream>>>(hidden, A_h, Wq, Wq_t, Wk, Wk_t, Wv, Wv_t, Wo, Wo_t);
    // 2) fused QKV projection
    gemm8_bf16<<<dim3(M / 256, 3072 / 256), 512, 0, stream>>>(
        A_h, Wq_t, q_f32, kv_f32, 3072, 2048);
    // 3) Q-norm-rope + K-norm-rope + V transpose in one launch
    fused_norm_v<<<22528, 256, 0, stream>>>(q_f32, q_bf, kv_f32, k_bf, vt_bf, qw, kw);
    // 4) attention (v8, split into two dispatches by batch for profiling)
    flash_attn<<<dim3(16, NH_), 256, 0, stream>>>(q_bf, k_bf, vt_bf, attn_bf, 0);
    flash_attn<<<dim3(16, NH_), 256, 0, stream>>>(q_bf, k_bf, vt_bf, attn_bf, 1);
    // 5) O projection
    gemm_o<<<dim3(M / 128, 2048 / 256), 512, 0, stream>>>(attn_bf, Wo_t, out);
}

// Round 9
// 295.810 us; speedup vs baseline: 1.1039x; 1.1039x over previous
//
#include <hip/hip_runtime.h>
#include <hip/hip_bf16.h>

#define B_  2
#define L_  2048
#define HS_ 2048
#define NH_ 16
#define NKV_ 4
#define HD_ 128
#define EPS_ 1e-6f
#define SCALE_ 0.08838834764831843f
#define LOG2E_ 1.4426950408889634f

typedef __attribute__((ext_vector_type(8))) short bf16x8;
typedef __attribute__((ext_vector_type(4))) float f32x4;

__device__ __forceinline__ f32x4 mfma16(bf16x8 a, bf16x8 b, f32x4 c) {
    return __builtin_amdgcn_mfma_f32_16x16x32_bf16(a, b, c, 0, 0, 0);
}

__device__ __forceinline__ void async_copy16(void* lds, const void* g) {
    __builtin_amdgcn_global_load_lds(
        (const __attribute__((address_space(1))) unsigned int*)g,
        (__attribute__((address_space(3))) unsigned int*)lds,
        16, 0, 0);
}

// Single-instruction RNE f32 pair -> packed bf16.
__device__ __forceinline__ unsigned cvtpk(float lo, float hi) {
    unsigned r;
    asm("v_cvt_pk_bf16_f32 %0, %1, %2" : "=v"(r) : "v"(lo), "v"(hi));
    return r;
}

// ---------------------------------------------------------------------------
// fused_prep: one launch covering hidden cvt + 4 weight transposes.
__global__ __launch_bounds__(256) void fused_prep(
    const float* __restrict__ hidden, __hip_bfloat16* __restrict__ A_h,
    const float* __restrict__ Wq, __hip_bfloat16* __restrict__ Wq_t,
    const float* __restrict__ Wk, __hip_bfloat16* __restrict__ Wk_t,
    const float* __restrict__ Wv, __hip_bfloat16* __restrict__ Wv_t,
    const float* __restrict__ Wo, __hip_bfloat16* __restrict__ Wo_t) {
    __shared__ float tile[32][33];
    int bid = blockIdx.x;
    if (bid < 8192) {
        int i = bid * 256 + threadIdx.x;
        float4 v = ((const float4*)hidden)[i];
        union { __hip_bfloat16 h[4]; short4 s; } u;
        u.h[0] = __float2bfloat16(v.x);
        u.h[1] = __float2bfloat16(v.y);
        u.h[2] = __float2bfloat16(v.z);
        u.h[3] = __float2bfloat16(v.w);
        ((short4*)A_h)[i] = u.s;
        return;
    }
    const float* src; __hip_bfloat16* dst; int N, tb;
    if (bid < 12288)      { tb = bid - 8192;  src = Wq; dst = Wq_t; N = 2048; }
    else if (bid < 13312) { tb = bid - 12288; src = Wk; dst = Wk_t; N = 512;  }
    else if (bid < 14336) { tb = bid - 13312; src = Wv; dst = Wv_t; N = 512;  }
    else                  { tb = bid - 14336; src = Wo; dst = Wo_t; N = 2048; }
    int nt = N >> 5;
    int n0 = (tb % nt) * 32, k0 = (tb / nt) * 32;
    int tx = threadIdx.x & 31, ty = threadIdx.x >> 5;
#pragma unroll
    for (int i = 0; i < 32; i += 8)
        tile[ty + i][tx] = src[(size_t)(k0 + ty + i) * N + n0 + tx];
    __syncthreads();
#pragma unroll
    for (int i = 0; i < 32; i += 8)
        dst[(size_t)(n0 + ty + i) * HS_ + k0 + tx] = __float2bfloat16(tile[tx][ty + i]);
}

// ---------------------------------------------------------------------------
// fused_norm_v: Q norm_rope + K norm_rope + V transpose in one launch.
__device__ __forceinline__ void norm_rope_row(const float* __restrict__ X,
                                              __hip_bfloat16* __restrict__ Y,
                                              const float* __restrict__ w,
                                              int row, int lane,
                                              int log2nh, int in_stride, float oscale) {
    int m = row >> log2nh;
    int head = row & ((1 << log2nh) - 1);
    int pos = m & (L_ - 1);
    const float* x = X + (size_t)m * in_stride + head * HD_;
    float x1 = x[lane], x2 = x[lane + 64];
    float ss = x1 * x1 + x2 * x2;
#pragma unroll
    for (int mm = 1; mm < 64; mm <<= 1) ss += __shfl_xor(ss, mm);
    float rms = rsqrtf(ss * (1.0f / 128.0f) + EPS_);
    float xn1 = x1 * rms * w[lane];
    float xn2 = x2 * rms * w[lane + 64];
    float inv_freq = __builtin_exp2f(-(float)lane * 0.20762050593046014f);
    float ang = (float)pos * inv_freq;
    float c = cosf(ang), s = sinf(ang);
    __hip_bfloat16* y = Y + (size_t)row * HD_;
    y[lane]      = __float2bfloat16((xn1 * c - xn2 * s) * oscale);
    y[lane + 64] = __float2bfloat16((xn2 * c + xn1 * s) * oscale);
}

__global__ __launch_bounds__(256) void fused_norm_v(
    const float* __restrict__ q_f32, __hip_bfloat16* __restrict__ q_bf,
    const float* __restrict__ kv_f32, __hip_bfloat16* __restrict__ k_bf,
    __hip_bfloat16* __restrict__ vt_bf,
    const float* __restrict__ qw, const float* __restrict__ kw) {
    __shared__ float tile[32][33];
    int bid = blockIdx.x;
    int lane = threadIdx.x & 63;
    if (bid < 16384) {
        int row = bid * 4 + (threadIdx.x >> 6);
        norm_rope_row(q_f32, q_bf, qw, row, lane, 4, 2048, SCALE_ * LOG2E_);
        return;
    }
    if (bid < 20480) {
        int row = (bid - 16384) * 4 + (threadIdx.x >> 6);
        norm_rope_row(kv_f32, k_bf, kw, row, lane, 2, 1024, 1.0f);
        return;
    }
    int vbid = bid - 20480;
    int xb = vbid & 63, yb = (vbid >> 6) & 3, zb = vbid >> 8;
    int b = zb >> 2, kv = zb & 3;
    int l0 = xb * 32, d0 = yb * 32;
    int tx = threadIdx.x & 31, ty = threadIdx.x >> 5;
#pragma unroll
    for (int i = 0; i < 32; i += 8)
        tile[ty + i][tx] = kv_f32[(size_t)(b * L_ + l0 + ty + i) * 1024 + 512 + kv * HD_ + d0 + tx];
    __syncthreads();
#pragma unroll
    for (int i = 0; i < 32; i += 8)
        vt_bf[((size_t)(b * NKV_ + kv) * HD_ + d0 + ty + i) * L_ + l0 + tx] =
            __float2bfloat16(tile[tx][ty + i]);
}

// ---------------------------------------------------------------------------
// gemm_db<BN, SPLIT>: 128xBN tile, BK=64, 256 threads (4 waves, 2Mx2N),
// double-buffered LDS = 2*(16KB + BN*128B) -> 80KB (BN=192) or 64KB (BN=128)
// => 2 blocks/CU. Latency hiding comes from the co-resident partner block
// (m97/m114 mechanism): when this block stalls on its counted vmcnt, the
// other block's waves issue MFMAs.
// LDS: A region buf*16384 + row*128 + slot*16 (rows 0..127);
//      B region 32768 + buf*(BN*128) + row*128 + slot*16 (rows 0..BN-1).
// Swizzle invariant (verified in gemm8): LDS slot s at row r holds global
// K-slot s^(r&7); staged with linear dest + pre-swizzled source
// sl=(t&7)^((t>>3)&7) (all staged rowbases are multiples of 8... 0/32/64/96).
// Per K-tile, 2 phases:
//   p0: a(mi 0..1) + b(all NI) reads; stage B(T+1) [NB copies]; MFMA m-half 0.
//       wait vmcnt(2): retires B(T) all + A(T) copies {rows 0-31, 64-95}.
//   p1: a(mi 2..3) reads (b reused from regs); stage A(T+1) [4 copies,
//       rowbase order {0,64,32,96}]; MFMA m-half 1.
//       wait vmcnt(NB): retires A(T) copies {rows 32-63, 96-127}.
// Never drains to 0. b-fragments loaded once per K-tile, reused both phases.
#define GNT 32
#define GKB 4096   // K=2048 * 2B row stride
template<int BN, bool SPLIT>
__global__ __launch_bounds__(256, 2) void gemm_db(const __hip_bfloat16* __restrict__ A,
                                                  const __hip_bfloat16* __restrict__ Bt,
                                                  float* __restrict__ C1,
                                                  float* __restrict__ C2) {
    constexpr int NB = BN / 32;        // B copies per tile (6 or 4)
    constexpr int NI = BN / 32;        // n-fragments per wave ((BN/2)/16)
    constexpr int BUFA = 16384;        // 128 rows * 128 B
    constexpr int BUFB = BN * 128;
    __shared__ __align__(16) char lds[2 * BUFA + 2 * BUFB];
    int t = threadIdx.x;
    int w = t >> 6, lane = t & 63;
    int row16 = lane & 15, quad = lane >> 4, e7 = row16 & 7;
    int wr = w >> 1, wc = w & 1;

    // bijective XCD swizzle (nwg = 512, multiple of 8)
    int gx = gridDim.x;
    int nwg = gx * gridDim.y;
    int bid = blockIdx.y * gx + blockIdx.x;
    int cpx = nwg >> 3;
    int swz = (bid & 7) * cpx + (bid >> 3);
    int bx = swz % gx, by = swz / gx;
    int m0 = bx * 128, n0 = by * BN;

    // reader bases (per kc K-half)
    const char* baseA[2];
    const char* baseB[2];
#pragma unroll
    for (int kc = 0; kc < 2; ++kc) {
        int so = ((kc * 4 + quad) ^ e7) << 4;
        baseA[kc] = lds + (wr * 64 + row16) * 128 + so;
        baseB[kc] = lds + 2 * BUFA + (wc * (BN / 2) + row16) * 128 + so;
    }

    // staging bases: thread t covers row r8 = t>>3 (0..31) of each 32-row copy
    int r8 = t >> 3;
    int sl = (t & 7) ^ (r8 & 7);
    char* dA = lds + r8 * 128 + (t & 7) * 16;
    char* dB = lds + 2 * BUFA + r8 * 128 + (t & 7) * 16;
    const char* gA = (const char*)A + (size_t)(m0 + r8) * GKB + sl * 16;
    const char* gB = (const char*)Bt + (size_t)(n0 + r8) * GKB + sl * 16;
    // A copy i -> rowbase {0, 64, 32, 96}: p0 needs copies 0,1; p1 needs 2,3.
    const int arow[4] = {0, 64, 32, 96};

    f32x4 acc[4][NI] = {};
    bf16x8 a[2][2], b[NI][2];

    // prologue: tile 0 -> buf0: B copies then A copies
#pragma unroll
    for (int j = 0; j < NB; ++j) async_copy16(dB + j * 4096, gB + (size_t)j * 32 * GKB);
#pragma unroll
    for (int i = 0; i < 4; ++i) async_copy16(dA + arow[i] * 128, gA + (size_t)arow[i] * GKB);

    for (int T = 0; T < GNT; ++T) {
        const int cuA = (T & 1) * BUFA, duA = ((T + 1) & 1) * BUFA;
        const int cuB = (T & 1) * BUFB, duB = ((T + 1) & 1) * BUFB;
        const int tn = (T + 1 < GNT ? T + 1 : T) * 128;

        // ---------------- phase 0: m-half 0 ----------------
        asm volatile("s_waitcnt vmcnt(2)" ::: "memory");
        __builtin_amdgcn_s_barrier();
        __builtin_amdgcn_sched_barrier(0);
#pragma unroll
        for (int mi = 0; mi < 2; ++mi)
#pragma unroll
            for (int kc = 0; kc < 2; ++kc)
                a[mi][kc] = *(const bf16x8*)(baseA[kc] + cuA + mi * 2048);
#pragma unroll
        for (int ni = 0; ni < NI; ++ni)
#pragma unroll
            for (int kc = 0; kc < 2; ++kc)
                b[ni][kc] = *(const bf16x8*)(baseB[kc] + cuB + ni * 2048);
#pragma unroll
        for (int j = 0; j < NB; ++j)
            async_copy16(dB + duB + j * 4096, gB + (size_t)j * 32 * GKB + tn);
        asm volatile("s_waitcnt lgkmcnt(0)" ::: "memory");
        __builtin_amdgcn_sched_barrier(0);
        __builtin_amdgcn_s_setprio(1);
#pragma unroll
        for (int mi = 0; mi < 2; ++mi)
#pragma unroll
            for (int ni = 0; ni < NI; ++ni)
#pragma unroll
                for (int kc = 0; kc < 2; ++kc)
                    acc[mi][ni] = mfma16(a[mi][kc], b[ni][kc], acc[mi][ni]);
        __builtin_amdgcn_s_setprio(0);

        // ---------------- phase 1: m-half 1 (b reused from regs) ----------------
        asm volatile("s_waitcnt vmcnt(%0)" :: "i"(NB) : "memory");
        __builtin_amdgcn_s_barrier();
        __builtin_amdgcn_sched_barrier(0);
#pragma unroll
        for (int mi = 0; mi < 2; ++mi)
#pragma unroll
            for (int kc = 0; kc < 2; ++kc)
                a[mi][kc] = *(const bf16x8*)(baseA[kc] + cuA + 4096 + mi * 2048);
#pragma unroll
        for (int i = 0; i < 4; ++i)
            async_copy16(dA + duA + arow[i] * 128, gA + (size_t)arow[i] * GKB + tn);
        asm volatile("s_waitcnt lgkmcnt(0)" ::: "memory");
        __builtin_amdgcn_sched_barrier(0);
        __builtin_amdgcn_s_setprio(1);
#pragma unroll
        for (int mi = 0; mi < 2; ++mi)
#pragma unroll
            for (int ni = 0; ni < NI; ++ni)
#pragma unroll
                for (int kc = 0; kc < 2; ++kc)
                    acc[2 + mi][ni] = mfma16(a[mi][kc], b[ni][kc], acc[2 + mi][ni]);
        __builtin_amdgcn_s_setprio(0);
    }
    asm volatile("s_waitcnt vmcnt(0)" ::: "memory");

    // epilogue
#pragma unroll
    for (int mi = 0; mi < 4; ++mi)
#pragma unroll
        for (int ni = 0; ni < NI; ++ni) {
            int rbase = m0 + wr * 64 + mi * 16 + quad * 4;
            int col = n0 + wc * (BN / 2) + ni * 16 + row16;
            if (SPLIT) {
                if (col < 2048) {
#pragma unroll
                    for (int r = 0; r < 4; ++r)
                        C1[(size_t)(rbase + r) * 2048 + col] = acc[mi][ni][r];
                } else {
#pragma unroll
                    for (int r = 0; r < 4; ++r)
                        C2[(size_t)(rbase + r) * 1024 + (col - 2048)] = acc[mi][ni][r];
                }
            } else {
#pragma unroll
                for (int r = 0; r < 4; ++r)
                    C1[(size_t)(rbase + r) * 2048 + col] = acc[mi][ni][r];
            }
        }
}

// ---------------------------------------------------------------------------
// Flash attention v8 (verified 4-wave x 16-row structure, single dispatch).
__global__ __launch_bounds__(256, 2) void flash_attn(const __hip_bfloat16* __restrict__ Q,
                                                     const __hip_bfloat16* __restrict__ Kb,
                                                     const __hip_bfloat16* __restrict__ Vt,
                                                     __hip_bfloat16* __restrict__ O) {
    __shared__ __align__(16) __hip_bfloat16 sK[2][64 * 128];
    __shared__ __align__(16) __hip_bfloat16 sV[2][128 * 64];
    __shared__ __align__(16) __hip_bfloat16 sP[4][16 * 72];

    int t = threadIdx.x, wave = t >> 6, lane = t & 63;
    int row16 = lane & 15, quad = lane >> 4;
    int h = blockIdx.y, b = blockIdx.z;
    int kv = h & (NKV_ - 1);
    int x = blockIdx.x;
    int qtA = x, qtB = 31 - x;
    int nA = qtA + 1;
    const int nTot = 33;

    int e7 = row16 & 7;
    int kOff[4], vOff[2];
#pragma unroll
    for (int kc = 0; kc < 4; ++kc)
        kOff[kc] = row16 * 256 + (((kc * 4 + quad) ^ e7) * 16);
#pragma unroll
    for (int kc2 = 0; kc2 < 2; ++kc2)
        vOff[kc2] = row16 * 128 + (((kc2 * 4 + quad) ^ e7) * 16);

    const char* sKb = (const char*)&sK[0][0];
    const char* sVb = (const char*)&sV[0][0];
    char* myP = (char*)&sP[wave][0];
    int pW = row16 * 144 + quad * 8;
    int pR = row16 * 144 + quad * 16;

    const char* gK[4];
    const char* gV[4];
#pragma unroll
    for (int i = 0; i < 4; ++i) {
        int rk = wave * 16 + i * 4 + quad;
        int ck = row16 ^ (rk & 7);
        gK[i] = (const char*)(Kb + ((size_t)(b * L_ + rk) * NKV_ + kv) * HD_ + ck * 8);
        int rv = wave * 32 + i * 8 + (lane >> 3);
        int cv = (lane & 7) ^ (rv & 7);
        gV[i] = (const char*)(Vt + ((size_t)(b * NKV_ + kv) * HD_ + rv) * L_ + cv * 8);
    }
    char* dK = (char*)&sK[0][0] + wave * 4096 + lane * 16;
    char* dV = (char*)&sV[0][0] + wave * 4096 + lane * 16;

    bf16x8 qf[4];
    f32x4 accO[8];
    float lrow;
    int q0w = 0;

    auto loadQ = [&](int qt) {
        q0w = qt * 64 + wave * 16;
        const __hip_bfloat16* qbase =
            Q + ((size_t)(b * L_ + q0w + row16) * NH_ + h) * HD_ + quad * 8;
#pragma unroll
        for (int kc = 0; kc < 4; ++kc) qf[kc] = *(const bf16x8*)(qbase + kc * 32);
#pragma unroll
        for (int db = 0; db < 8; ++db) accO[db] = f32x4{0.f, 0.f, 0.f, 0.f};
        lrow = 0.f;
    };

    auto epilogue = [&]() {
        float l = lrow;
        l += __shfl_xor(l, 16);
        l += __shfl_xor(l, 32);
        float linv = 1.0f / l;
        __hip_bfloat16* obase = O + ((size_t)(b * L_ + q0w + row16) * NH_ + h) * HD_;
#pragma unroll
        for (int db = 0; db < 8; ++db) {
            union { __hip_bfloat16 h4[4]; short4 s4; } u;
#pragma unroll
            for (int r = 0; r < 4; ++r) u.h4[r] = __float2bfloat16(accO[db][r] * linv);
            *(short4*)(obase + db * 16 + quad * 4) = u.s4;
        }
    };

    auto stage = [&](int s1) {
        int kb64 = (s1 < nA ? s1 : s1 - nA) * 64;
        int buf = (s1 & 1) * 16384;
        int ko = kb64 * 1024;
        int vo = kb64 * 2;
#pragma unroll
        for (int i = 0; i < 4; ++i) {
            async_copy16(dK + buf + i * 1024, gK[i] + ko);
            async_copy16(dV + buf + i * 1024, gV[i] + vo);
        }
    };

    loadQ(qtA);
    stage(0);
    for (int s = 0; s < nTot; ++s) {
        __syncthreads();
        if (s + 1 < nTot) stage(s + 1);
        if (s == nA) { epilogue(); loadQ(qtB); }
        int kcur = (s < nA ? s : s - nA) * 64;
        const char* cK = sKb + (s & 1) * 16384;
        const char* cV = sVb + (s & 1) * 16384;

        f32x4 st[4];
        __builtin_amdgcn_s_setprio(1);
#pragma unroll
        for (int kb = 0; kb < 4; ++kb) {
            f32x4 acc = {};
#pragma unroll
            for (int kc = 0; kc < 4; ++kc) {
                bf16x8 kf = *(const bf16x8*)(cK + kb * 4096 + kOff[kc]);
                acc = mfma16(kf, qf[kc], acc);
            }
            st[kb] = acc;
        }
        __builtin_amdgcn_s_setprio(0);

        float p[4][4];
        if (kcur + 63 > q0w) {
            int qgRel = q0w + row16 - kcur - quad * 4;
#pragma unroll
            for (int kb = 0; kb < 4; ++kb)
#pragma unroll
                for (int r = 0; r < 4; ++r) {
                    float e = __builtin_exp2f(st[kb][r]);
                    p[kb][r] = (kb * 16 + r <= qgRel) ? e : 0.f;
                }
        } else {
#pragma unroll
            for (int kb = 0; kb < 4; ++kb)
#pragma unroll
                for (int r = 0; r < 4; ++r)
                    p[kb][r] = __builtin_exp2f(st[kb][r]);
        }
#pragma unroll
        for (int kb = 0; kb < 4; ++kb)
#pragma unroll
            for (int r = 0; r < 4; ++r) lrow += p[kb][r];

#pragma unroll
        for (int kb = 0; kb < 4; ++kb) {
            uint2 u;
            u.x = cvtpk(p[kb][0], p[kb][1]);
            u.y = cvtpk(p[kb][2], p[kb][3]);
            *(uint2*)(myP + pW + kb * 32) = u;
        }
        asm volatile("s_waitcnt lgkmcnt(0)" ::: "memory");
        bf16x8 pf[2];
        pf[0] = *(const bf16x8*)(myP + pR);
        pf[1] = *(const bf16x8*)(myP + pR + 64);

        __builtin_amdgcn_s_setprio(1);
#pragma unroll
        for (int db = 0; db < 8; ++db) {
#pragma unroll
            for (int kc2 = 0; kc2 < 2; ++kc2) {
                bf16x8 vf = *(const bf16x8*)(cV + db * 2048 + vOff[kc2]);
                accO[db] = mfma16(vf, pf[kc2], accO[db]);
            }
        }
        __builtin_amdgcn_s_setprio(0);
    }
    epilogue();
}

// ---------------------------------------------------------------------------
extern "C" void kernel_launch(void* const* d_in, const int* in_sizes, int n_in,
                              void* d_out, int out_size, void* d_ws, size_t ws_size,
                              hipStream_t stream) {
    const float* hidden = (const float*)d_in[0];
    const float* Wq = (const float*)d_in[1];
    const float* Wk = (const float*)d_in[2];
    const float* Wv = (const float*)d_in[3];
    const float* Wo = (const float*)d_in[4];
    const float* qw = (const float*)d_in[5];
    const float* kw = (const float*)d_in[6];
    float* out = (float*)d_out;

    char* ws = (char*)d_ws;
    size_t off = 0;
    auto alloc = [&](size_t bytes) { char* p = ws + off; off += (bytes + 255) & ~255ull; return p; };
    __hip_bfloat16* Wq_t = (__hip_bfloat16*)alloc((size_t)HS_ * NH_ * HD_ * 2);   // 8 MB
    __hip_bfloat16* Wk_t = (__hip_bfloat16*)alloc((size_t)HS_ * NKV_ * HD_ * 2);  // 2 MB (contiguous after Wq_t)
    __hip_bfloat16* Wv_t = (__hip_bfloat16*)alloc((size_t)HS_ * NKV_ * HD_ * 2);  // 2 MB (contiguous after Wk_t)
    __hip_bfloat16* Wo_t = (__hip_bfloat16*)alloc((size_t)HS_ * NH_ * HD_ * 2);   // 8 MB
    __hip_bfloat16* A_h  = (__hip_bfloat16*)alloc((size_t)B_ * L_ * HS_ * 2);     // 16 MB; reused as attn_bf
    float* kv_f32 = (float*)alloc((size_t)B_ * L_ * 1024 * 4);                    // 16 MB [M,1024] = K|V
    __hip_bfloat16* q_bf  = (__hip_bfloat16*)alloc((size_t)B_ * L_ * NH_ * HD_ * 2);
    __hip_bfloat16* k_bf  = (__hip_bfloat16*)alloc((size_t)B_ * L_ * NKV_ * HD_ * 2);
    __hip_bfloat16* vt_bf = (__hip_bfloat16*)alloc((size_t)B_ * NKV_ * HD_ * L_ * 2);
    float* q_f32 = out;                     // reuse d_out as pre-norm Q scratch
    __hip_bfloat16* attn_bf = A_h;

    const int M = B_ * L_;

    // 1) hidden cvt + all 4 weight transposes in one launch
    fused_prep<<<18432, 256, 0, stream>>>(hidden, A_h, Wq, Wq_t, Wk, Wk_t, Wv, Wv_t, Wo, Wo_t);
    // 2) fused QKV projection: 128x192 tile, 512 blocks = 2/CU
    gemm_db<192, true><<<dim3(M / 128, 3072 / 192), 256, 0, stream>>>(
        A_h, Wq_t, q_f32, kv_f32);
    // 3) Q-norm-rope + K-norm-rope + V transpose in one launch
    fused_norm_v<<<22528, 256, 0, stream>>>(q_f32, q_bf, kv_f32, k_bf, vt_bf, qw, kw);
    // 4) attention (v8, single dispatch: 512 blocks = 2/CU)
    flash_attn<<<dim3(16, NH_, B_), 256, 0, stream>>>(q_bf, k_bf, vt_bf, attn_bf);
    // 5) O projection: 128x128 tile, 512 blocks = 2/CU
    gemm_db<128, false><<<dim3(M / 128, 2048 / 128), 256, 0, stream>>>(
        attn_bf, Wo_t, out, nullptr);
}